// Round 1
// baseline (417.359 us; speedup 1.0000x reference)
//
#include <hip/hip_runtime.h>
#include <math.h>

#define NODE_DIM 64
#define EDGE_DIM 16
#define HEADS 4
#define CDIM 16
#define CAP 64
#define NEG_SLOPE 0.2f
#define BN_EPS 1e-5f

__device__ __forceinline__ float wave_max64(float v) {
#pragma unroll
    for (int o = 32; o; o >>= 1) v = fmaxf(v, __shfl_xor(v, o, 64));
    return v;
}
__device__ __forceinline__ float wave_sum64(float v) {
#pragma unroll
    for (int o = 32; o; o >>= 1) v += __shfl_xor(v, o, 64);
    return v;
}
__device__ __forceinline__ float lrelu(float s) {
    return fmaxf(s, 0.f) + NEG_SLOPE * fminf(s, 0.f);
}

// K1: xl = x@Wl + bl ; xr = x@Wr + br. One wave per row, lane = column.
__global__ __launch_bounds__(256) void k_transform(
    const float* __restrict__ x, const float* __restrict__ Wl,
    const float* __restrict__ bl, const float* __restrict__ Wr,
    const float* __restrict__ br, float* __restrict__ xl,
    float* __restrict__ xr, int n)
{
    __shared__ float sWl[NODE_DIM * NODE_DIM];
    __shared__ float sWr[NODE_DIM * NODE_DIM];
    for (int i = threadIdx.x; i < NODE_DIM * NODE_DIM; i += 256) {
        sWl[i] = Wl[i];
        sWr[i] = Wr[i];
    }
    __syncthreads();
    int t = blockIdx.x * 256 + threadIdx.x;
    int row = t >> 6;
    int col = t & 63;
    if (row >= n) return;
    float xown = x[row * NODE_DIM + col];
    float al = bl[col], ar = br[col];
#pragma unroll
    for (int k = 0; k < NODE_DIM; k++) {
        float xv = __shfl(xown, k, 64);
        al = fmaf(xv, sWl[k * 64 + col], al);
        ar = fmaf(xv, sWr[k * 64 + col], ar);
    }
    xl[t] = al;
    xr[t] = ar;
}

// K2: per-edge logits + dst histogram
__global__ __launch_bounds__(256) void k_edge(
    const int* __restrict__ ei, const float* __restrict__ eattr,
    const float* __restrict__ We, const float* __restrict__ att,
    const float* __restrict__ xl, const float* __restrict__ xr,
    float* __restrict__ logits, int* __restrict__ counts, int E)
{
    int e = blockIdx.x * 256 + threadIdx.x;
    if (e >= E) return;
    int src = ei[e], dst = ei[E + e];

    float ea[EDGE_DIM];
    const float4* ea4 = (const float4*)(eattr + (size_t)e * EDGE_DIM);
#pragma unroll
    for (int k4 = 0; k4 < 4; k4++) {
        float4 v = ea4[k4];
        ea[k4 * 4 + 0] = v.x; ea[k4 * 4 + 1] = v.y;
        ea[k4 * 4 + 2] = v.z; ea[k4 * 4 + 3] = v.w;
    }

    float4 acc[16];
#pragma unroll
    for (int j = 0; j < 16; j++) acc[j] = make_float4(0.f, 0.f, 0.f, 0.f);

    const float4* We4 = (const float4*)We;  // [16 rows][16 float4]
#pragma unroll
    for (int k = 0; k < EDGE_DIM; k++) {
        float a = ea[k];
#pragma unroll
        for (int j = 0; j < 16; j++) {
            float4 w = We4[k * 16 + j];
            acc[j].x = fmaf(a, w.x, acc[j].x);
            acc[j].y = fmaf(a, w.y, acc[j].y);
            acc[j].z = fmaf(a, w.z, acc[j].z);
            acc[j].w = fmaf(a, w.w, acc[j].w);
        }
    }

    const float4* xl4 = (const float4*)(xl + (size_t)src * NODE_DIM);
    const float4* xr4 = (const float4*)(xr + (size_t)dst * NODE_DIM);
    const float4* att4 = (const float4*)att;
    float lg[HEADS] = {0.f, 0.f, 0.f, 0.f};
#pragma unroll
    for (int j = 0; j < 16; j++) {
        float4 l4 = xl4[j], r4 = xr4[j], a4 = att4[j];
        int h = j >> 2;
        float sx = acc[j].x + l4.x + r4.x;
        float sy = acc[j].y + l4.y + r4.y;
        float sz = acc[j].z + l4.z + r4.z;
        float sw = acc[j].w + l4.w + r4.w;
        float g = fmaf(lrelu(sx), a4.x,
                  fmaf(lrelu(sy), a4.y,
                  fmaf(lrelu(sz), a4.z,
                       lrelu(sw) * a4.w)));
        lg[h] += g;
    }
    ((float4*)logits)[e] = make_float4(lg[0], lg[1], lg[2], lg[3]);
    atomicAdd(&counts[dst], 1);
}

// K3: bucket edges by dst
__global__ __launch_bounds__(256) void k_scatter(
    const int* __restrict__ ei, int* __restrict__ cursors,
    int* __restrict__ slots, int E)
{
    int e = blockIdx.x * 256 + threadIdx.x;
    if (e >= E) return;
    int dst = ei[E + e];
    int pos = atomicAdd(&cursors[dst], 1);
    if (pos < CAP) slots[(size_t)dst * CAP + pos] = e;
}

// K4: one wave per node: segment softmax + weighted aggregation
__global__ __launch_bounds__(64) void k_node(
    const int* __restrict__ ei, const int* __restrict__ counts,
    const int* __restrict__ slots, const float* __restrict__ logits,
    const float* __restrict__ xl, const float* __restrict__ bias,
    float* __restrict__ out, int n)
{
    int i = blockIdx.x;
    int lane = threadIdx.x;
    int deg = counts[i];
    if (deg > CAP) deg = CAP;

    int src = 0;
    float4 lg = make_float4(-1e30f, -1e30f, -1e30f, -1e30f);
    if (lane < deg) {
        int eid = slots[(size_t)i * CAP + lane];
        src = ei[eid];
        lg = ((const float4*)logits)[eid];
    }
    float m0 = wave_max64(lg.x), m1 = wave_max64(lg.y);
    float m2 = wave_max64(lg.z), m3 = wave_max64(lg.w);
    bool act = (lane < deg);
    float e0 = act ? __expf(lg.x - m0) : 0.f;
    float e1 = act ? __expf(lg.y - m1) : 0.f;
    float e2 = act ? __expf(lg.z - m2) : 0.f;
    float e3 = act ? __expf(lg.w - m3) : 0.f;
    float s0 = wave_sum64(e0), s1 = wave_sum64(e1);
    float s2 = wave_sum64(e2), s3 = wave_sum64(e3);
    float a0 = e0 / (s0 + 1e-16f);
    float a1 = e1 / (s1 + 1e-16f);
    float a2 = e2 / (s2 + 1e-16f);
    float a3 = e3 / (s3 + 1e-16f);

    int h = lane >> 4;
    float acc = 0.f;
    for (int t = 0; t < deg; t++) {
        int sT = __shfl(src, t, 64);
        float b0 = __shfl(a0, t, 64);
        float b1 = __shfl(a1, t, 64);
        float b2 = __shfl(a2, t, 64);
        float b3 = __shfl(a3, t, 64);
        float lo = (h & 1) ? b1 : b0;
        float hi = (h & 1) ? b3 : b2;
        float a = (h & 2) ? hi : lo;
        acc = fmaf(a, xl[(size_t)sT * NODE_DIM + lane], acc);
    }
    out[(size_t)i * NODE_DIM + lane] = acc + bias[lane];
}

// K5: column sums / sumsq for BatchNorm
__global__ __launch_bounds__(256) void k_bnstat(
    const float* __restrict__ out, float* __restrict__ stats, int n)
{
    __shared__ float sbuf[256];
    int col = threadIdx.x & 63;
    int rgrp = threadIdx.x >> 6;
    float s = 0.f, q = 0.f;
    for (int row = blockIdx.x * 4 + rgrp; row < n; row += gridDim.x * 4) {
        float v = out[(size_t)row * 64 + col];
        s += v;
        q = fmaf(v, v, q);
    }
    sbuf[threadIdx.x] = s;
    __syncthreads();
    if (threadIdx.x < 64) {
        s = sbuf[threadIdx.x] + sbuf[threadIdx.x + 64] +
            sbuf[threadIdx.x + 128] + sbuf[threadIdx.x + 192];
        atomicAdd(&stats[col], s);
    }
    __syncthreads();
    sbuf[threadIdx.x] = q;
    __syncthreads();
    if (threadIdx.x < 64) {
        q = sbuf[threadIdx.x] + sbuf[threadIdx.x + 64] +
            sbuf[threadIdx.x + 128] + sbuf[threadIdx.x + 192];
        atomicAdd(&stats[64 + col], q);
    }
}

// K6: BN normalize + residual + exact GELU, in place on d_out
__global__ __launch_bounds__(256) void k_final(
    float* __restrict__ out, const float* __restrict__ x,
    const float* __restrict__ stats, const float* __restrict__ gamma,
    const float* __restrict__ beta, int total, float invn)
{
    int i = blockIdx.x * 256 + threadIdx.x;
    if (i >= total) return;
    int c = i & 63;
    float mean = stats[c] * invn;
    float var = stats[64 + c] * invn - mean * mean;
    float z = (out[i] - mean) * rsqrtf(var + BN_EPS) * gamma[c] + beta[c] + x[i];
    out[i] = z * 0.5f * (1.f + erff(z * 0.70710678118654752f));
}

extern "C" void kernel_launch(void* const* d_in, const int* in_sizes, int n_in,
                              void* d_out, int out_size, void* d_ws, size_t ws_size,
                              hipStream_t stream)
{
    const float* x     = (const float*)d_in[0];
    const int*   ei    = (const int*)d_in[1];
    const float* eattr = (const float*)d_in[2];
    const float* Wl    = (const float*)d_in[3];
    const float* bl    = (const float*)d_in[4];
    const float* Wr    = (const float*)d_in[5];
    const float* br    = (const float*)d_in[6];
    const float* We    = (const float*)d_in[7];
    const float* att   = (const float*)d_in[8];
    const float* bias  = (const float*)d_in[9];
    const float* gamma = (const float*)d_in[10];
    const float* beta  = (const float*)d_in[11];
    int n = in_sizes[0] / NODE_DIM;
    int E = in_sizes[1] / 2;

    char* ws = (char*)d_ws;
    float* xl     = (float*)ws; ws += (size_t)n * NODE_DIM * 4;
    float* xr     = (float*)ws; ws += (size_t)n * NODE_DIM * 4;
    float* logits = (float*)ws; ws += (size_t)E * HEADS * 4;
    int*   slots  = (int*)ws;   ws += (size_t)n * CAP * 4;
    int*   counts = (int*)ws;   ws += (size_t)n * 4;
    int*   cursors= (int*)ws;   ws += (size_t)n * 4;
    float* stats  = (float*)ws; ws += 128 * 4;

    // zero counts + cursors + stats (they are contiguous)
    hipMemsetAsync(counts, 0, (size_t)(2 * n + 128) * 4, stream);

    k_transform<<<(n * NODE_DIM + 255) / 256, 256, 0, stream>>>(
        x, Wl, bl, Wr, br, xl, xr, n);
    k_edge<<<(E + 255) / 256, 256, 0, stream>>>(
        ei, eattr, We, att, xl, xr, logits, counts, E);
    k_scatter<<<(E + 255) / 256, 256, 0, stream>>>(ei, cursors, slots, E);
    k_node<<<n, 64, 0, stream>>>(
        ei, counts, slots, logits, xl, bias, (float*)d_out, n);
    k_bnstat<<<256, 256, 0, stream>>>((const float*)d_out, stats, n);
    k_final<<<(n * NODE_DIM + 255) / 256, 256, 0, stream>>>(
        (float*)d_out, x, stats, gamma, beta, n * NODE_DIM, 1.0f / n);
}

// Round 2
// 267.368 us; speedup vs baseline: 1.5610x; 1.5610x over previous
//
#include <hip/hip_runtime.h>
#include <math.h>

#define NODE_DIM 64
#define EDGE_DIM 16
#define HEADS 4
#define CAP 64
#define NEG_SLOPE 0.2f
#define BN_EPS 1e-5f
#define SXL_STRIDE 68  // ushorts; 136B rows: 8B-aligned chunks, 4-way max write conflict

typedef unsigned short ushort_t;

__device__ __forceinline__ float wave_max64(float v) {
#pragma unroll
    for (int o = 32; o; o >>= 1) v = fmaxf(v, __shfl_xor(v, o, 64));
    return v;
}
__device__ __forceinline__ float wave_sum64(float v) {
#pragma unroll
    for (int o = 32; o; o >>= 1) v += __shfl_xor(v, o, 64);
    return v;
}
__device__ __forceinline__ float lrelu(float s) {
    return fmaxf(s, 0.f) + NEG_SLOPE * fminf(s, 0.f);
}
__device__ __forceinline__ ushort_t f2bf(float f) {  // round-to-nearest-even
    unsigned int b = __float_as_uint(f);
    b += 0x7FFFu + ((b >> 16) & 1u);
    return (ushort_t)(b >> 16);
}
__device__ __forceinline__ float bf2f(ushort_t u) {
    return __uint_as_float(((unsigned int)u) << 16);
}

// K1: xl = x@Wl + bl ; xr = x@Wr + br. Grid-stride; one wave per row.
__global__ __launch_bounds__(256) void k_transform(
    const float* __restrict__ x, const float* __restrict__ Wl,
    const float* __restrict__ bl, const float* __restrict__ Wr,
    const float* __restrict__ br, float* __restrict__ xl,
    float* __restrict__ xr, int n)
{
    __shared__ float sWl[NODE_DIM * NODE_DIM];
    __shared__ float sWr[NODE_DIM * NODE_DIM];
    for (int i = threadIdx.x; i < NODE_DIM * NODE_DIM; i += 256) {
        sWl[i] = Wl[i];
        sWr[i] = Wr[i];
    }
    __syncthreads();
    int lane = threadIdx.x & 63;
    int wid = threadIdx.x >> 6;
    for (int row = blockIdx.x * 4 + wid; row < n; row += gridDim.x * 4) {
        float xown = x[(size_t)row * NODE_DIM + lane];
        float al = bl[lane], ar = br[lane];
#pragma unroll
        for (int k = 0; k < NODE_DIM; k++) {
            float xv = __shfl(xown, k, 64);
            al = fmaf(xv, sWl[k * 64 + lane], al);
            ar = fmaf(xv, sWr[k * 64 + lane], ar);
        }
        xl[(size_t)row * NODE_DIM + lane] = al;
        xr[(size_t)row * NODE_DIM + lane] = ar;
    }
}

// K2: bucket edges by dst; store (src, eid) packed. cursors end as degree.
__global__ __launch_bounds__(256) void k_scatter(
    const int* __restrict__ ei, int* __restrict__ cursors,
    int2* __restrict__ slot2, int E)
{
    int e = blockIdx.x * 256 + threadIdx.x;
    if (e >= E) return;
    int src = ei[e];
    int dst = ei[E + e];
    int pos = atomicAdd(&cursors[dst], 1);
    if (pos < CAP) slot2[(size_t)dst * CAP + pos] = make_int2(src, e);
}

// K3 (fused): per dst node (1 wave): edge logits + segment softmax + aggregation.
// lane = edge for phases A/B, lane = channel for phase C.
__global__ __launch_bounds__(64) void k_fused(
    const int2* __restrict__ slot2, const int* __restrict__ cursors,
    const float* __restrict__ eattr, const float* __restrict__ We,
    const float* __restrict__ att, const float* __restrict__ xl,
    const float* __restrict__ xr, const float* __restrict__ bias,
    float* __restrict__ out, int n)
{
    __shared__ ushort_t sxl[64 * SXL_STRIDE];
    __shared__ float salpha[64 * 4];

    int i = blockIdx.x;
    int lane = threadIdx.x;
    int deg = cursors[i];
    if (deg > CAP) deg = CAP;
    bool act = (lane < deg);

    int2 se = act ? slot2[(size_t)i * CAP + lane] : make_int2(0, 0);
    int src = se.x, eid = se.y;

    // per-lane edge attr (64B)
    float ea[EDGE_DIM];
    {
        const float4* ea4 = (const float4*)(eattr + (size_t)eid * EDGE_DIM);
#pragma unroll
        for (int k4 = 0; k4 < 4; k4++) {
            float4 v = ea4[k4];
            ea[k4 * 4 + 0] = v.x; ea[k4 * 4 + 1] = v.y;
            ea[k4 * 4 + 2] = v.z; ea[k4 * 4 + 3] = v.w;
        }
    }

    // gather this edge's xl row (the single global gather of xl)
    const float4* xl4 = (const float4*)(xl + (size_t)src * NODE_DIM);
    float4 xlr[16];
#pragma unroll
    for (int j = 0; j < 16; j++) xlr[j] = xl4[j];

    // wave-uniform rows: xr[dst], att, We (scalar/broadcast loads)
    const float4* xr4 = (const float4*)(xr + (size_t)i * NODE_DIM);
    const float4* att4 = (const float4*)att;
    const float4* We4 = (const float4*)We;  // [16 rows][16 float4]

    float lg[HEADS] = {0.f, 0.f, 0.f, 0.f};
#pragma unroll
    for (int j = 0; j < 16; j++) {
        float4 acc = make_float4(0.f, 0.f, 0.f, 0.f);
#pragma unroll
        for (int k = 0; k < EDGE_DIM; k++) {
            float a = ea[k];
            float4 w = We4[k * 16 + j];
            acc.x = fmaf(a, w.x, acc.x);
            acc.y = fmaf(a, w.y, acc.y);
            acc.z = fmaf(a, w.z, acc.z);
            acc.w = fmaf(a, w.w, acc.w);
        }
        float4 r4 = xr4[j], a4 = att4[j], l4 = xlr[j];
        float sx = l4.x + r4.x + acc.x;
        float sy = l4.y + r4.y + acc.y;
        float sz = l4.z + r4.z + acc.z;
        float sw = l4.w + r4.w + acc.w;
        lg[j >> 2] += fmaf(lrelu(sx), a4.x,
                      fmaf(lrelu(sy), a4.y,
                      fmaf(lrelu(sz), a4.z,
                           lrelu(sw) * a4.w)));
        // stash xl row chunk to LDS as bf16 (row = lane, 17 ushort4 per row)
        ushort4 u4;
        u4.x = f2bf(l4.x); u4.y = f2bf(l4.y);
        u4.z = f2bf(l4.z); u4.w = f2bf(l4.w);
        ((ushort4*)sxl)[lane * (SXL_STRIDE / 4) + j] = u4;
    }

    // phase B: segment softmax across lanes (lane = edge)
    float l0 = act ? lg[0] : -1e30f;
    float l1 = act ? lg[1] : -1e30f;
    float l2 = act ? lg[2] : -1e30f;
    float l3 = act ? lg[3] : -1e30f;
    float m0 = wave_max64(l0), m1 = wave_max64(l1);
    float m2 = wave_max64(l2), m3 = wave_max64(l3);
    float e0 = act ? __expf(l0 - m0) : 0.f;
    float e1 = act ? __expf(l1 - m1) : 0.f;
    float e2 = act ? __expf(l2 - m2) : 0.f;
    float e3 = act ? __expf(l3 - m3) : 0.f;
    float s0 = wave_sum64(e0), s1 = wave_sum64(e1);
    float s2 = wave_sum64(e2), s3 = wave_sum64(e3);
    float4 al4 = make_float4(e0 / (s0 + 1e-16f), e1 / (s1 + 1e-16f),
                             e2 / (s2 + 1e-16f), e3 / (s3 + 1e-16f));
    ((float4*)salpha)[lane] = al4;

    __syncthreads();

    // phase C: lane = channel; aggregate from LDS
    int h = lane >> 4;
    float acc = 0.f;
    for (int t = 0; t < deg; t++) {
        float a = salpha[t * 4 + h];
        acc = fmaf(a, bf2f(sxl[t * SXL_STRIDE + lane]), acc);
    }
    out[(size_t)i * NODE_DIM + lane] = acc + bias[lane];
}

// K4: column sums / sumsq for BatchNorm
__global__ __launch_bounds__(256) void k_bnstat(
    const float* __restrict__ out, float* __restrict__ stats, int n)
{
    __shared__ float sbuf[256];
    int col = threadIdx.x & 63;
    int rgrp = threadIdx.x >> 6;
    float s = 0.f, q = 0.f;
    for (int row = blockIdx.x * 4 + rgrp; row < n; row += gridDim.x * 4) {
        float v = out[(size_t)row * 64 + col];
        s += v;
        q = fmaf(v, v, q);
    }
    sbuf[threadIdx.x] = s;
    __syncthreads();
    if (threadIdx.x < 64) {
        s = sbuf[threadIdx.x] + sbuf[threadIdx.x + 64] +
            sbuf[threadIdx.x + 128] + sbuf[threadIdx.x + 192];
        atomicAdd(&stats[col], s);
    }
    __syncthreads();
    sbuf[threadIdx.x] = q;
    __syncthreads();
    if (threadIdx.x < 64) {
        q = sbuf[threadIdx.x] + sbuf[threadIdx.x + 64] +
            sbuf[threadIdx.x + 128] + sbuf[threadIdx.x + 192];
        atomicAdd(&stats[64 + col], q);
    }
}

// K5: BN normalize + residual + exact GELU, in place on d_out
__global__ __launch_bounds__(256) void k_final(
    float* __restrict__ out, const float* __restrict__ x,
    const float* __restrict__ stats, const float* __restrict__ gamma,
    const float* __restrict__ beta, int total, float invn)
{
    int i = blockIdx.x * 256 + threadIdx.x;
    if (i >= total) return;
    int c = i & 63;
    float mean = stats[c] * invn;
    float var = stats[64 + c] * invn - mean * mean;
    float z = (out[i] - mean) * rsqrtf(var + BN_EPS) * gamma[c] + beta[c] + x[i];
    out[i] = z * 0.5f * (1.f + erff(z * 0.70710678118654752f));
}

extern "C" void kernel_launch(void* const* d_in, const int* in_sizes, int n_in,
                              void* d_out, int out_size, void* d_ws, size_t ws_size,
                              hipStream_t stream)
{
    const float* x     = (const float*)d_in[0];
    const int*   ei    = (const int*)d_in[1];
    const float* eattr = (const float*)d_in[2];
    const float* Wl    = (const float*)d_in[3];
    const float* bl    = (const float*)d_in[4];
    const float* Wr    = (const float*)d_in[5];
    const float* br    = (const float*)d_in[6];
    const float* We    = (const float*)d_in[7];
    const float* att   = (const float*)d_in[8];
    const float* bias  = (const float*)d_in[9];
    const float* gamma = (const float*)d_in[10];
    const float* beta  = (const float*)d_in[11];
    int n = in_sizes[0] / NODE_DIM;
    int E = in_sizes[1] / 2;

    char* ws = (char*)d_ws;
    float* xl     = (float*)ws; ws += (size_t)n * NODE_DIM * 4;
    float* xr     = (float*)ws; ws += (size_t)n * NODE_DIM * 4;
    int2*  slot2  = (int2*)ws;  ws += (size_t)n * CAP * 8;
    int*   cursors= (int*)ws;   ws += (size_t)n * 4;
    float* stats  = (float*)ws; ws += 128 * 4;

    // zero cursors + stats (contiguous)
    hipMemsetAsync(cursors, 0, (size_t)(n + 128) * 4, stream);

    k_transform<<<512, 256, 0, stream>>>(x, Wl, bl, Wr, br, xl, xr, n);
    k_scatter<<<(E + 255) / 256, 256, 0, stream>>>(ei, cursors, slot2, E);
    k_fused<<<n, 64, 0, stream>>>(slot2, cursors, eattr, We, att, xl, xr,
                                  bias, (float*)d_out, n);
    k_bnstat<<<256, 256, 0, stream>>>((const float*)d_out, stats, n);
    k_final<<<(n * NODE_DIM + 255) / 256, 256, 0, stream>>>(
        (float*)d_out, x, stats, gamma, beta, n * NODE_DIM, 1.0f / n);
}

// Round 3
// 261.855 us; speedup vs baseline: 1.5939x; 1.0211x over previous
//
#include <hip/hip_runtime.h>
#include <math.h>

#define NODE_DIM 64
#define EDGE_DIM 16
#define HEADS 4
#define CAP 64
#define NEG_SLOPE 0.2f
#define BN_EPS 1e-5f

typedef unsigned short ushort_t;

__device__ __forceinline__ float wave_max64(float v) {
#pragma unroll
    for (int o = 32; o; o >>= 1) v = fmaxf(v, __shfl_xor(v, o, 64));
    return v;
}
__device__ __forceinline__ float wave_sum64(float v) {
#pragma unroll
    for (int o = 32; o; o >>= 1) v += __shfl_xor(v, o, 64);
    return v;
}
__device__ __forceinline__ float lrelu(float s) {
    return fmaxf(s, 0.f) + NEG_SLOPE * fminf(s, 0.f);
}
__device__ __forceinline__ ushort_t f2bf(float f) {  // round-to-nearest-even
    unsigned int b = __float_as_uint(f);
    b += 0x7FFFu + ((b >> 16) & 1u);
    return (ushort_t)(b >> 16);
}
__device__ __forceinline__ float bf2f(ushort_t u) {
    return __uint_as_float(((unsigned int)u) << 16);
}

// K1: xr = x@Wr + br (f32) ; xlbf = bf16(x@Wl + bl). One wave per row.
__global__ __launch_bounds__(256) void k_transform(
    const float* __restrict__ x, const float* __restrict__ Wl,
    const float* __restrict__ bl, const float* __restrict__ Wr,
    const float* __restrict__ br, ushort_t* __restrict__ xlbf,
    float* __restrict__ xr, int n)
{
    __shared__ float sWl[NODE_DIM * NODE_DIM];
    __shared__ float sWr[NODE_DIM * NODE_DIM];
    for (int i = threadIdx.x; i < NODE_DIM * NODE_DIM; i += 256) {
        sWl[i] = Wl[i];
        sWr[i] = Wr[i];
    }
    __syncthreads();
    int lane = threadIdx.x & 63;
    int wid = threadIdx.x >> 6;
    for (int row = blockIdx.x * 4 + wid; row < n; row += gridDim.x * 4) {
        float xown = x[(size_t)row * NODE_DIM + lane];
        float al = bl[lane], ar = br[lane];
#pragma unroll
        for (int k = 0; k < NODE_DIM; k++) {
            float xv = __shfl(xown, k, 64);
            al = fmaf(xv, sWl[k * 64 + lane], al);
            ar = fmaf(xv, sWr[k * 64 + lane], ar);
        }
        xlbf[(size_t)row * NODE_DIM + lane] = f2bf(al);
        xr[(size_t)row * NODE_DIM + lane] = ar;
    }
}

// K2: bucket edges by dst; store (src, eid) packed. cursors end as degree.
__global__ __launch_bounds__(256) void k_scatter(
    const int* __restrict__ ei, int* __restrict__ cursors,
    int2* __restrict__ slot2, int E)
{
    int e = blockIdx.x * 256 + threadIdx.x;
    if (e >= E) return;
    int src = ei[e];
    int dst = ei[E + e];
    int pos = atomicAdd(&cursors[dst], 1);
    if (pos < CAP) slot2[(size_t)dst * CAP + pos] = make_int2(src, e);
}

// K3 (fused): per dst node (1 wave).
// Phase A: lane = CHANNEL, loop t over edges (all 64 lanes active).
// Phase B: lane = edge, wave softmax. Phase C: lane = channel, aggregate.
__global__ __launch_bounds__(64) void k_fused(
    const int2* __restrict__ slot2, const int* __restrict__ cursors,
    const float* __restrict__ eattr, const float* __restrict__ We,
    const float* __restrict__ att, const ushort_t* __restrict__ xlbf,
    const float* __restrict__ xr, const float* __restrict__ bias,
    float* __restrict__ out, int n)
{
    __shared__ ushort_t sxl[CAP * 64];   // bf16 xl rows, [t][channel]
    __shared__ float slog[CAP * 4];      // logits [t][head]
    __shared__ float salpha[CAP * 4];    // alpha  [t][head]

    int i = blockIdx.x;
    int lane = threadIdx.x;
    int deg = cursors[i];
    if (deg > CAP) deg = CAP;
    bool act = (lane < deg);

    int2 se = act ? slot2[(size_t)i * CAP + lane] : make_int2(0, 0);
    int se_x = se.x, se_y = se.y;

    // per-lane channel constants
    float xr_c = xr[(size_t)i * NODE_DIM + lane];
    float att_c = att[lane];              // att[h][c] flat == lane
    float we_c[EDGE_DIM];
#pragma unroll
    for (int k = 0; k < EDGE_DIM; k++) we_c[k] = We[k * NODE_DIM + lane];

    int h = lane >> 4;

#define BODY(T) {                                                        \
        int src_t = __builtin_amdgcn_readlane(se_x, (T));                \
        int eid_t = __builtin_amdgcn_readlane(se_y, (T));                \
        const float* ear = eattr + (size_t)eid_t * EDGE_DIM;             \
        float p = 0.f;                                                   \
        _Pragma("unroll")                                                \
        for (int k = 0; k < EDGE_DIM; k++) p = fmaf(ear[k], we_c[k], p); \
        ushort_t xu = xlbf[(size_t)src_t * NODE_DIM + lane];             \
        float s = bf2f(xu) + xr_c + p;                                   \
        float g = lrelu(s) * att_c;                                      \
        g += __shfl_xor(g, 1, 64);                                       \
        g += __shfl_xor(g, 2, 64);                                       \
        g += __shfl_xor(g, 4, 64);                                       \
        g += __shfl_xor(g, 8, 64);                                       \
        sxl[(T) * 64 + lane] = xu;                                       \
        if ((lane & 15) == 0) slog[(T) * 4 + h] = g;                     \
    }

    int t = 0;
    for (; t + 1 < deg; t += 2) { BODY(t); BODY(t + 1); }
    if (t < deg) BODY(t);
#undef BODY

    __syncthreads();

    // Phase B: lane = edge; wave softmax over deg lanes, 4 heads
    float4 lg = ((const float4*)slog)[lane];
    float l0 = act ? lg.x : -1e30f;
    float l1 = act ? lg.y : -1e30f;
    float l2 = act ? lg.z : -1e30f;
    float l3 = act ? lg.w : -1e30f;
    float m0 = wave_max64(l0), m1 = wave_max64(l1);
    float m2 = wave_max64(l2), m3 = wave_max64(l3);
    float e0 = act ? __expf(l0 - m0) : 0.f;
    float e1 = act ? __expf(l1 - m1) : 0.f;
    float e2 = act ? __expf(l2 - m2) : 0.f;
    float e3 = act ? __expf(l3 - m3) : 0.f;
    float s0 = wave_sum64(e0), s1 = wave_sum64(e1);
    float s2 = wave_sum64(e2), s3 = wave_sum64(e3);
    ((float4*)salpha)[lane] = make_float4(
        e0 / (s0 + 1e-16f), e1 / (s1 + 1e-16f),
        e2 / (s2 + 1e-16f), e3 / (s3 + 1e-16f));

    __syncthreads();

    // Phase C: lane = channel; aggregate from LDS (2 accumulators for ILP)
    float acc0 = 0.f, acc1 = 0.f;
    int u = 0;
    for (; u + 1 < deg; u += 2) {
        float a0 = salpha[u * 4 + h];
        float a1 = salpha[(u + 1) * 4 + h];
        acc0 = fmaf(a0, bf2f(sxl[u * 64 + lane]), acc0);
        acc1 = fmaf(a1, bf2f(sxl[(u + 1) * 64 + lane]), acc1);
    }
    if (u < deg) acc0 = fmaf(salpha[u * 4 + h], bf2f(sxl[u * 64 + lane]), acc0);
    out[(size_t)i * NODE_DIM + lane] = acc0 + acc1 + bias[lane];
}

// K4: column sums / sumsq for BatchNorm
__global__ __launch_bounds__(256) void k_bnstat(
    const float* __restrict__ out, float* __restrict__ stats, int n)
{
    __shared__ float sbuf[256];
    int col = threadIdx.x & 63;
    int rgrp = threadIdx.x >> 6;
    float s = 0.f, q = 0.f;
    for (int row = blockIdx.x * 4 + rgrp; row < n; row += gridDim.x * 4) {
        float v = out[(size_t)row * 64 + col];
        s += v;
        q = fmaf(v, v, q);
    }
    sbuf[threadIdx.x] = s;
    __syncthreads();
    if (threadIdx.x < 64) {
        s = sbuf[threadIdx.x] + sbuf[threadIdx.x + 64] +
            sbuf[threadIdx.x + 128] + sbuf[threadIdx.x + 192];
        atomicAdd(&stats[col], s);
    }
    __syncthreads();
    sbuf[threadIdx.x] = q;
    __syncthreads();
    if (threadIdx.x < 64) {
        q = sbuf[threadIdx.x] + sbuf[threadIdx.x + 64] +
            sbuf[threadIdx.x + 128] + sbuf[threadIdx.x + 192];
        atomicAdd(&stats[64 + col], q);
    }
}

// K5: BN normalize + residual + exact GELU, in place on d_out
__global__ __launch_bounds__(256) void k_final(
    float* __restrict__ out, const float* __restrict__ x,
    const float* __restrict__ stats, const float* __restrict__ gamma,
    const float* __restrict__ beta, int total, float invn)
{
    int i = blockIdx.x * 256 + threadIdx.x;
    if (i >= total) return;
    int c = i & 63;
    float mean = stats[c] * invn;
    float var = stats[64 + c] * invn - mean * mean;
    float z = (out[i] - mean) * rsqrtf(var + BN_EPS) * gamma[c] + beta[c] + x[i];
    out[i] = z * 0.5f * (1.f + erff(z * 0.70710678118654752f));
}

extern "C" void kernel_launch(void* const* d_in, const int* in_sizes, int n_in,
                              void* d_out, int out_size, void* d_ws, size_t ws_size,
                              hipStream_t stream)
{
    const float* x     = (const float*)d_in[0];
    const int*   ei    = (const int*)d_in[1];
    const float* eattr = (const float*)d_in[2];
    const float* Wl    = (const float*)d_in[3];
    const float* bl    = (const float*)d_in[4];
    const float* Wr    = (const float*)d_in[5];
    const float* br    = (const float*)d_in[6];
    const float* We    = (const float*)d_in[7];
    const float* att   = (const float*)d_in[8];
    const float* bias  = (const float*)d_in[9];
    const float* gamma = (const float*)d_in[10];
    const float* beta  = (const float*)d_in[11];
    int n = in_sizes[0] / NODE_DIM;
    int E = in_sizes[1] / 2;

    char* ws = (char*)d_ws;
    float*    xr     = (float*)ws;    ws += (size_t)n * NODE_DIM * 4;
    ushort_t* xlbf   = (ushort_t*)ws; ws += (size_t)n * NODE_DIM * 2;
    int2*     slot2  = (int2*)ws;     ws += (size_t)n * CAP * 8;
    int*      cursors= (int*)ws;      ws += (size_t)n * 4;
    float*    stats  = (float*)ws;    ws += 128 * 4;

    // zero cursors + stats (contiguous)
    hipMemsetAsync(cursors, 0, (size_t)(n + 128) * 4, stream);

    k_transform<<<512, 256, 0, stream>>>(x, Wl, bl, Wr, br, xlbf, xr, n);
    k_scatter<<<(E + 255) / 256, 256, 0, stream>>>(ei, cursors, slot2, E);
    k_fused<<<n, 64, 0, stream>>>(slot2, cursors, eattr, We, att, xlbf, xr,
                                  bias, (float*)d_out, n);
    k_bnstat<<<256, 256, 0, stream>>>((const float*)d_out, stats, n);
    k_final<<<(n * NODE_DIM + 255) / 256, 256, 0, stream>>>(
        (float*)d_out, x, stats, gamma, beta, n * NODE_DIM, 1.0f / n);
}